// Round 7
// baseline (82.266 us; speedup 1.0000x reference)
//
#include <hip/hip_runtime.h>

// Problem constants (match reference): B=8, D=H=W=128, C=2, fp32.
constexpr int Bc = 8, Dc = 128, Hc = 128, Wc = 128;

// 16B vector load at 8B-aligned addresses: CDNA global loads require only
// dword alignment, so global_load_dwordx4 at float2 granularity is fine.
typedef float float4v __attribute__((ext_vector_type(4)));

// 8 consecutive d-slices per block: 8192 blocks = 8 resident WG/CU (32
// waves/CU) on 256 CUs. Interleaved dispatch preserved for XCD load balance
// (R4 lesson: batch-chunked swizzle -> XCD imbalance -> 23% regression).
constexpr int DPB = 8;

__global__ __launch_bounds__(256, 8) void affine_trilinear_kernel(
    const float* __restrict__ images,      // (B,D,H,W,C) fp32
    const float* __restrict__ mats,        // (B,3,4) fp32
    float2* __restrict__ out)              // (B,D,H,W,C) viewed as float2
{
    const int tid    = threadIdx.x;
    const int lane_w = tid & 63;           // 64 consecutive w per wave
    const int lane_h = tid >> 6;           // 4 h rows per block (L1 row reuse)

    const int bi = blockIdx.x;             // (b, d/8, h/4, w-half), NO swizzle
    const int wh = bi & 1;
    const int h4 = (bi >> 1) & 31;
    const int dg = (bi >> 6) & 15;
    const int b  = bi >> 10;               // uniform per block -> scalar loads

    const int w  = wh * 64 + lane_w;
    const int h  = h4 * 4 + lane_h;
    const int d0 = dg * DPB;

    const float* m = mats + b * 12;
    const float th00 = m[0] * 0.2f + 1.0f;
    const float th01 = m[1] * 0.2f;
    const float th02 = m[2] * 0.2f;
    const float th10 = m[4] * 0.2f;
    const float th11 = m[5] * 0.2f + 1.0f;
    const float th12 = m[6] * 0.2f;
    const float th20 = m[8] * 0.2f;
    const float th21 = m[9] * 0.2f;
    const float th22 = m[10] * 0.2f + 1.0f;
    const float t   = m[3] * 0.2f;                 // ref uses only m[0,3]
    const float off = 128.0f * (t + 0.5f) - 0.5f;  // dims are all 128

    // grid value: index - dim/2 - 0.5 = index - 64.5
    const float gy = (float)h - 64.5f;
    const float gz = (float)w - 64.5f;

    const float2* img = (const float2*)images + (size_t)b * (Dc * Hc * Wc);
    float2* po = out + ((((size_t)b * Dc + d0) * Hc + h) * Wc + w);

    #pragma unroll 2
    for (int it = 0; it < DPB; ++it) {
        const int   d  = d0 + it;
        const float gx = (float)d - 64.5f;

        // NUMERICS: keep this EXACT expression shape (verbatim from the
        // passing R1 kernel). The reference output is discontinuous at
        // r==127 (clamped-corner double-count), so any reassociation of
        // this sum can flip a voxel across it -> O(1) error (R5 lesson).
        const float r0 = gx * th00 + gy * th01 + gz * th02 + off;
        const float r1 = gx * th10 + gy * th11 + gz * th12 + off;
        const float r2 = gx * th20 + gy * th21 + gz * th22 + off;

        const int i0 = (int)floorf(r0);
        const int i1 = (int)floorf(r1);
        const int i2 = (int)floorf(r2);

        // d,h axes: per-corner clamped loc + weight (vs CLAMPED loc, per ref).
        const int l0a = min(max(i0,     0), Dc - 1);
        const int l0b = min(max(i0 + 1, 0), Dc - 1);
        const int l1a = min(max(i1,     0), Hc - 1);
        const int l1b = min(max(i1 + 1, 0), Hc - 1);

        const float w0a = fmaxf(1.0f - fabsf(r0 - (float)l0a), 0.0f);
        const float w0b = fmaxf(1.0f - fabsf(r0 - (float)l0b), 0.0f);
        const float w1a = fmaxf(1.0f - fabsf(r1 - (float)l1a), 0.0f);
        const float w1b = fmaxf(1.0f - fabsf(r1 - (float)l1b), 0.0f);

        // w axis: both corners from ONE 16B pair load at bp (float2 elems
        // bp, bp+1). Remap corner weights onto (lo,hi) of the pair:
        //   interior       : wlo = w2a, whi = w2b
        //   i2 < 0  (clamp): both at elem 0   -> wlo = w2a+w2b, whi = 0
        //   i2 > 126(clamp): both at elem 127 -> wlo = 0, whi = w2a+w2b
        const int bp  = min(max(i2, 0), Wc - 2);
        const int l2a = min(max(i2,     0), Wc - 1);
        const int l2b = min(max(i2 + 1, 0), Wc - 1);
        const float w2a = fmaxf(1.0f - fabsf(r2 - (float)l2a), 0.0f);
        const float w2b = fmaxf(1.0f - fabsf(r2 - (float)l2b), 0.0f);
        const float wlo = (i2 > 126) ? 0.0f        : (w2a + ((i2 < 0) ? w2b : 0.0f));
        const float whi = (i2 > 126) ? (w2a + w2b) : ((i2 < 0) ? 0.0f : w2b);

        // 32-bit element offsets (batch image = 2^21 float2): short v_mad
        // chains + SADDR-form loads.
        const unsigned rowA = (unsigned)(l0a * Hc + l1a) * Wc + bp;
        const unsigned rowB = (unsigned)(l0a * Hc + l1b) * Wc + bp;
        const unsigned rowC = (unsigned)(l0b * Hc + l1a) * Wc + bp;
        const unsigned rowD = (unsigned)(l0b * Hc + l1b) * Wc + bp;

        float acc0 = 0.0f, acc1 = 0.0f;
        {
            const float4v v = *(const float4v*)(img + rowA);
            const float wdh = w0a * w1a;
            acc0 = fmaf(v.x * wlo + v.z * whi, wdh, acc0);
            acc1 = fmaf(v.y * wlo + v.w * whi, wdh, acc1);
        }
        {
            const float4v v = *(const float4v*)(img + rowB);
            const float wdh = w0a * w1b;
            acc0 = fmaf(v.x * wlo + v.z * whi, wdh, acc0);
            acc1 = fmaf(v.y * wlo + v.w * whi, wdh, acc1);
        }
        {
            const float4v v = *(const float4v*)(img + rowC);
            const float wdh = w0b * w1a;
            acc0 = fmaf(v.x * wlo + v.z * whi, wdh, acc0);
            acc1 = fmaf(v.y * wlo + v.w * whi, wdh, acc1);
        }
        {
            const float4v v = *(const float4v*)(img + rowD);
            const float wdh = w0b * w1b;
            acc0 = fmaf(v.x * wlo + v.z * whi, wdh, acc0);
            acc1 = fmaf(v.y * wlo + v.w * whi, wdh, acc1);
        }

        *po = make_float2(acc0, acc1);
        po += Hc * Wc;                      // next d-slice
    }
}

extern "C" void kernel_launch(void* const* d_in, const int* in_sizes, int n_in,
                              void* d_out, int out_size, void* d_ws, size_t ws_size,
                              hipStream_t stream) {
    const float* images = (const float*)d_in[0];
    const float* mats   = (const float*)d_in[1];
    float2* out         = (float2*)d_out;

    const int threads = 256;
    const int blocks  = Bc * (Dc / DPB) * 32 * 2;  // 8192: (b, d/8, h/4, w-half)
    affine_trilinear_kernel<<<blocks, threads, 0, stream>>>(images, mats, out);
}

// Round 8
// 66.114 us; speedup vs baseline: 1.2443x; 1.2443x over previous
//
#include <hip/hip_runtime.h>

// Problem constants (match reference): B=8, D=H=W=128, C=2, fp32.
constexpr int Bc = 8, Dc = 128, Hc = 128, Wc = 128;

// 16B vector load at 8B-aligned addresses: CDNA global loads require only
// dword alignment, so global_load_dwordx4 at float2 granularity is fine.
typedef float float4v __attribute__((ext_vector_type(4)));

// Structure = R1 (66.8us champion): 256 thr = 4 waves x 4 h-rows, one voxel
// per thread, 65536 blocks, plain store, NO swizzle (R4: XCD-chunk -> batch
// imbalance), NO d-loop (R6: serial chain stalls), NO 2-voxel burst (R2).
// New in R7: wave-uniform interior fast path (cheap weights + addressing).
__global__ __launch_bounds__(256) void affine_trilinear_kernel(
    const float* __restrict__ images,      // (B,D,H,W,C) fp32
    const float* __restrict__ mats,        // (B,3,4) fp32
    float2* __restrict__ out)              // (B,D,H,W,C) viewed as float2
{
    const int tid    = threadIdx.x;
    const int lane_w = tid & 63;           // 64 consecutive w per wave
    const int lane_h = tid >> 6;           // 4 h rows per block (L1 row reuse)

    const int bi = blockIdx.x;
    const int wh = bi & 1;                 // which w half
    const int h4 = (bi >> 1) & 31;
    const int d  = (bi >> 6) & (Dc - 1);
    const int b  = bi >> 13;               // uniform per block -> scalar loads

    const int w = wh * 64 + lane_w;
    const int h = h4 * 4 + lane_h;

    const float* m = mats + b * 12;
    const float th00 = m[0] * 0.2f + 1.0f;
    const float th01 = m[1] * 0.2f;
    const float th02 = m[2] * 0.2f;
    const float th10 = m[4] * 0.2f;
    const float th11 = m[5] * 0.2f + 1.0f;
    const float th12 = m[6] * 0.2f;
    const float th20 = m[8] * 0.2f;
    const float th21 = m[9] * 0.2f;
    const float th22 = m[10] * 0.2f + 1.0f;
    const float t   = m[3] * 0.2f;                 // ref uses only m[0,3]
    const float off = 128.0f * (t + 0.5f) - 0.5f;  // dims are all 128

    // grid value: index - dim/2 - 0.5 = index - 64.5
    const float gx = (float)d - 64.5f;
    const float gy = (float)h - 64.5f;
    const float gz = (float)w - 64.5f;

    // NUMERICS: keep this EXACT expression shape (verbatim from passing R1).
    // The reference output is discontinuous where a coord crosses 127
    // (clamped-corner double-count), so reassociation can flip a voxel
    // across it -> O(1) error (R5 lesson). i0/i1/i2 derive ONLY from these.
    const float r0 = gx * th00 + gy * th01 + gz * th02 + off;
    const float r1 = gx * th10 + gy * th11 + gz * th12 + off;
    const float r2 = gx * th20 + gy * th21 + gz * th22 + off;

    const int i0 = (int)floorf(r0);
    const int i1 = (int)floorf(r1);
    const int i2 = (int)floorf(r2);

    const float2* img = (const float2*)images + (size_t)b * (Dc * Hc * Wc);

    float acc0 = 0.0f, acc1 = 0.0f;

    // Interior: both corners in-range on every axis for every lane of the
    // wave -> no clamping anywhere, weights are plain (1-f, f), and the four
    // corner rows sit at fixed offsets from one base. ~85-90% of waves.
    const bool interior = ((unsigned)i0 <= 126u) & ((unsigned)i1 <= 126u) &
                          ((unsigned)i2 <= 126u);
    if (__all(interior)) {
        // Exact fractional parts (Sterbenz: r - floor(r) exact in fp32).
        const float f0 = r0 - (float)i0;
        const float f1 = r1 - (float)i1;
        const float f2 = r2 - (float)i2;
        const float w0a = 1.0f - f0;
        const float w1a = 1.0f - f1;
        const float wlo = 1.0f - f2;       // == ref w2a bit-exactly
        const float whi = f2;              // ref w2b differs <= 2^-24: harmless

        const unsigned rowA = (unsigned)(i0 * Hc + i1) * Wc + i2;
        const unsigned rowB = rowA + Wc;           // (i0, i1+1)
        const unsigned rowC = rowA + Hc * Wc;      // (i0+1, i1)
        const unsigned rowD = rowC + Wc;           // (i0+1, i1+1)

        const float4v vA = *(const float4v*)(img + rowA);
        const float4v vB = *(const float4v*)(img + rowB);
        const float4v vC = *(const float4v*)(img + rowC);
        const float4v vD = *(const float4v*)(img + rowD);

        const float wA = w0a * w1a;
        const float wB = w0a * f1;
        const float wC = f0 * w1a;
        const float wD = f0 * f1;

        acc0 = fmaf(vA.x * wlo + vA.z * whi, wA, acc0);
        acc1 = fmaf(vA.y * wlo + vA.w * whi, wA, acc1);
        acc0 = fmaf(vB.x * wlo + vB.z * whi, wB, acc0);
        acc1 = fmaf(vB.y * wlo + vB.w * whi, wB, acc1);
        acc0 = fmaf(vC.x * wlo + vC.z * whi, wC, acc0);
        acc1 = fmaf(vC.y * wlo + vC.w * whi, wC, acc1);
        acc0 = fmaf(vD.x * wlo + vD.z * whi, wD, acc0);
        acc1 = fmaf(vD.y * wlo + vD.w * whi, wD, acc1);
    } else {
        // Slow path: R1-verbatim general case (clamped corners, weights vs
        // CLAMPED location, per reference).
        const int l0a = min(max(i0,     0), Dc - 1);
        const int l0b = min(max(i0 + 1, 0), Dc - 1);
        const int l1a = min(max(i1,     0), Hc - 1);
        const int l1b = min(max(i1 + 1, 0), Hc - 1);

        const float w0a = fmaxf(1.0f - fabsf(r0 - (float)l0a), 0.0f);
        const float w0b = fmaxf(1.0f - fabsf(r0 - (float)l0b), 0.0f);
        const float w1a = fmaxf(1.0f - fabsf(r1 - (float)l1a), 0.0f);
        const float w1b = fmaxf(1.0f - fabsf(r1 - (float)l1b), 0.0f);

        // w axis: both corners from ONE 16B pair load at bp (float2 elems
        // bp, bp+1):
        //   interior       : wlo = w2a, whi = w2b
        //   i2 < 0  (clamp): both at elem 0   -> wlo = w2a+w2b, whi = 0
        //   i2 > 126(clamp): both at elem 127 -> wlo = 0, whi = w2a+w2b
        const int bp  = min(max(i2, 0), Wc - 2);
        const int l2a = min(max(i2,     0), Wc - 1);
        const int l2b = min(max(i2 + 1, 0), Wc - 1);
        const float w2a = fmaxf(1.0f - fabsf(r2 - (float)l2a), 0.0f);
        const float w2b = fmaxf(1.0f - fabsf(r2 - (float)l2b), 0.0f);
        const float wlo = (i2 > 126) ? 0.0f        : (w2a + ((i2 < 0) ? w2b : 0.0f));
        const float whi = (i2 > 126) ? (w2a + w2b) : ((i2 < 0) ? 0.0f : w2b);

        const unsigned rowA = (unsigned)(l0a * Hc + l1a) * Wc + bp;
        const unsigned rowB = (unsigned)(l0a * Hc + l1b) * Wc + bp;
        const unsigned rowC = (unsigned)(l0b * Hc + l1a) * Wc + bp;
        const unsigned rowD = (unsigned)(l0b * Hc + l1b) * Wc + bp;

        const float4v vA = *(const float4v*)(img + rowA);
        const float4v vB = *(const float4v*)(img + rowB);
        const float4v vC = *(const float4v*)(img + rowC);
        const float4v vD = *(const float4v*)(img + rowD);

        acc0 = fmaf(vA.x * wlo + vA.z * whi, w0a * w1a, acc0);
        acc1 = fmaf(vA.y * wlo + vA.w * whi, w0a * w1a, acc1);
        acc0 = fmaf(vB.x * wlo + vB.z * whi, w0a * w1b, acc0);
        acc1 = fmaf(vB.y * wlo + vB.w * whi, w0a * w1b, acc1);
        acc0 = fmaf(vC.x * wlo + vC.z * whi, w0b * w1a, acc0);
        acc1 = fmaf(vC.y * wlo + vC.w * whi, w0b * w1a, acc1);
        acc0 = fmaf(vD.x * wlo + vD.z * whi, w0b * w1b, acc0);
        acc1 = fmaf(vD.y * wlo + vD.w * whi, w0b * w1b, acc1);
    }

    out[(((size_t)b * Dc + d) * Hc + h) * Wc + w] = make_float2(acc0, acc1);
}

extern "C" void kernel_launch(void* const* d_in, const int* in_sizes, int n_in,
                              void* d_out, int out_size, void* d_ws, size_t ws_size,
                              hipStream_t stream) {
    const float* images = (const float*)d_in[0];
    const float* mats   = (const float*)d_in[1];
    float2* out         = (float2*)d_out;

    const int threads = 256;
    const int blocks  = Bc * Dc * 32 * 2;  // 65536: (b, d, h/4, w-half)
    affine_trilinear_kernel<<<blocks, threads, 0, stream>>>(images, mats, out);
}